// Round 1
// baseline (1876.299 us; speedup 1.0000x reference)
//
#include <hip/hip_runtime.h>
#include <hip/hip_bf16.h>

typedef __bf16 bf16_t;
typedef __bf16 bf16x8 __attribute__((ext_vector_type(8)));
typedef float f32x4 __attribute__((ext_vector_type(4)));

#define SEQ 2048
#define HID 2048
#define NH 16
#define DH 128
#define BATCH 2

__device__ __forceinline__ unsigned short f2bf(float f) {
  return __builtin_bit_cast(unsigned short, (__bf16)f);
}

// ---------------- cast fp32 -> bf16 ----------------
__global__ void k_cast_bf16(const float4* __restrict__ in, ushort4* __restrict__ out, int n4) {
  int i = blockIdx.x * 256 + threadIdx.x;
  if (i >= n4) return;
  float4 v = in[i];
  ushort4 o;
  o.x = f2bf(v.x); o.y = f2bf(v.y); o.z = f2bf(v.z); o.w = f2bf(v.w);
  out[i] = o;
}

// ---------------- bias row means (*0.1) ----------------
__global__ void k_bmean(const float* __restrict__ bias, float* __restrict__ bm) {
  int s = blockIdx.x;
  int t = threadIdx.x;
  const float4* row = (const float4*)(bias + (size_t)s * SEQ);
  float acc = 0.f;
  for (int c = t; c < SEQ / 4; c += 256) { float4 v = row[c]; acc += (v.x + v.y) + (v.z + v.w); }
  for (int off = 1; off < 64; off <<= 1) acc += __shfl_xor(acc, off);
  __shared__ float red[4];
  if ((t & 63) == 0) red[t >> 6] = acc;
  __syncthreads();
  if (t == 0) bm[s] = (red[0] + red[1] + red[2] + red[3]) * (0.1f / SEQ);
}

// ---------------- GEMM: C[M,N] = A[M,K] @ B[N,K]^T (both row-major bf16) ----------------
// EPI 0: fp32 row-major; EPI 1: bf16 row-major; EPI 2: bf16 stored as V-transposed [b,h,d,s]
template <int EPI>
__global__ __launch_bounds__(256, 2) void k_gemm_bt(const bf16_t* __restrict__ A,
                                                    const bf16_t* __restrict__ B,
                                                    void* __restrict__ C,
                                                    int M, int N, int K) {
  __shared__ ushort As[128 * 72];
  __shared__ ushort Bs[128 * 72];
  const int tid = threadIdx.x;
  const int lane = tid & 63, wave = tid >> 6;
  const int m16 = lane & 15, quad = lane >> 4;
  const int wm = (wave >> 1) * 64, wn = (wave & 1) * 64;
  const int bm0 = blockIdx.y * 128, bn0 = blockIdx.x * 128;

  f32x4 acc[4][4];
  for (int i = 0; i < 4; ++i)
    for (int j = 0; j < 4; ++j) acc[i][j] = (f32x4){0.f, 0.f, 0.f, 0.f};

  uint4 ra[4], rb[4];
  auto gload = [&](int kt) {
    size_t k0 = (size_t)kt * 64;
    for (int it = 0; it < 4; ++it) {
      int g = it * 256 + tid, r = g >> 3, c = (g & 7) * 8;
      ra[it] = *(const uint4*)(A + (size_t)(bm0 + r) * K + k0 + c);
      rb[it] = *(const uint4*)(B + (size_t)(bn0 + r) * K + k0 + c);
    }
  };
  gload(0);
  const int NT = K / 64;
  for (int kt = 0; kt < NT; ++kt) {
    __syncthreads();
    for (int it = 0; it < 4; ++it) {
      int g = it * 256 + tid, r = g >> 3, c = (g & 7) * 8;
      *(uint4*)&As[r * 72 + c] = ra[it];
      *(uint4*)&Bs[r * 72 + c] = rb[it];
    }
    __syncthreads();
    if (kt + 1 < NT) gload(kt + 1);
    for (int ks = 0; ks < 2; ++ks) {
      bf16x8 af[4], bf_[4];
      for (int i = 0; i < 4; ++i)
        af[i] = *(const bf16x8*)&As[(wm + i * 16 + m16) * 72 + ks * 32 + quad * 8];
      for (int j = 0; j < 4; ++j)
        bf_[j] = *(const bf16x8*)&Bs[(wn + j * 16 + m16) * 72 + ks * 32 + quad * 8];
      for (int i = 0; i < 4; ++i)
        for (int j = 0; j < 4; ++j)
          acc[i][j] = __builtin_amdgcn_mfma_f32_16x16x32_bf16(af[i], bf_[j], acc[i][j], 0, 0, 0);
    }
  }
  for (int i = 0; i < 4; ++i)
    for (int j = 0; j < 4; ++j)
      for (int r = 0; r < 4; ++r) {
        int row = bm0 + wm + i * 16 + quad * 4 + r;
        int col = bn0 + wn + j * 16 + m16;
        float v = acc[i][j][r];
        if (EPI == 0) {
          ((float*)C)[(size_t)row * N + col] = v;
        } else if (EPI == 1) {
          ((bf16_t*)C)[(size_t)row * N + col] = (bf16_t)v;
        } else {
          int b = row >> 11, s = row & (SEQ - 1);
          int h = col >> 7, d = col & (DH - 1);
          ((bf16_t*)C)[(((size_t)(b * NH + h)) * DH + d) * SEQ + s] = (bf16_t)v;
        }
      }
}

// ---------------- RoPE + bmean, fp32 -> bf16 ----------------
__global__ void k_rope(const float* __restrict__ Qf, const float* __restrict__ Kf,
                       const float* __restrict__ bm,
                       bf16_t* __restrict__ Qb, bf16_t* __restrict__ Kb) {
  int idx = blockIdx.x * 256 + threadIdx.x;  // 4096 rows * 1024 pairs
  int row = idx >> 10, p = idx & 1023;
  int h = p >> 6, i = p & 63;
  int s = row & (SEQ - 1);
  float invf = powf(10000.f, -(float)i * (1.f / 64.f));
  float ang = (float)s * invf;
  float sn, cs;
  sincosf(ang, &sn, &cs);
  float b = bm[s];
  size_t o1 = (size_t)row * HID + h * DH + i;
  size_t o2 = o1 + 64;
  float q1 = Qf[o1], q2 = Qf[o2];
  Qb[o1] = (bf16_t)(q1 * cs - q2 * sn + b);
  Qb[o2] = (bf16_t)(q2 * cs + q1 * sn + b);
  float k1 = Kf[o1], k2 = Kf[o2];
  Kb[o1] = (bf16_t)(k1 * cs - k2 * sn + b);
  Kb[o2] = (bf16_t)(k2 * cs + k1 * sn + b);
}

// ---------------- attention: scores+softmax+P-write+PV ----------------
__global__ __launch_bounds__(256, 2) void k_attn(const bf16_t* __restrict__ Qb,
                                                 const bf16_t* __restrict__ Kb,
                                                 const bf16_t* __restrict__ Vt,
                                                 const float* __restrict__ bias,
                                                 float* __restrict__ P,
                                                 bf16_t* __restrict__ AO) {
  __shared__ ushort Qs[64 * 136];
  __shared__ ushort Ks[64 * 136];
  __shared__ ushort Vs[128 * 72];
  __shared__ ushort Ps[64 * 72];
  __shared__ float m_s[64], l_s[64];

  const int tid = threadIdx.x;
  const int lane = tid & 63, wave = tid >> 6;
  const int m16 = lane & 15, quad = lane >> 4;
  const int qb = (int)gridDim.x - 1 - (int)blockIdx.x;  // big blocks first
  const int h = blockIdx.y, b = blockIdx.z;
  const int q0 = qb * 64;
  const int wq = wave * 16;
  const float scale = 0.08838834764831845f;  // 1/sqrt(128)

  const bf16_t* Qg = Qb + ((size_t)(b * SEQ + q0)) * HID + h * DH;
  for (int it = 0; it < 4; ++it) {
    int g = it * 256 + tid, r = g >> 4, c = (g & 15) * 8;
    *(uint4*)&Qs[r * 136 + c] = *(const uint4*)(Qg + (size_t)r * HID + c);
  }
  if (tid < 64) { m_s[tid] = -1e30f; l_s[tid] = 0.f; }
  __syncthreads();

  // ---- phase 1: row max / sumexp ----
  for (int kt = 0; kt <= qb; ++kt) {
    if (kt) __syncthreads();
    const bf16_t* Kg = Kb + ((size_t)(b * SEQ + kt * 64)) * HID + h * DH;
    for (int it = 0; it < 4; ++it) {
      int g = it * 256 + tid, r = g >> 4, c = (g & 15) * 8;
      *(uint4*)&Ks[r * 136 + c] = *(const uint4*)(Kg + (size_t)r * HID + c);
    }
    __syncthreads();

    f32x4 sc[4];
    for (int j = 0; j < 4; ++j) sc[j] = (f32x4){0.f, 0.f, 0.f, 0.f};
    for (int ks = 0; ks < 4; ++ks) {
      bf16x8 af = *(const bf16x8*)&Qs[(wq + m16) * 136 + ks * 32 + quad * 8];
      for (int j = 0; j < 4; ++j) {
        bf16x8 bf_ = *(const bf16x8*)&Ks[(j * 16 + m16) * 136 + ks * 32 + quad * 8];
        sc[j] = __builtin_amdgcn_mfma_f32_16x16x32_bf16(af, bf_, sc[j], 0, 0, 0);
      }
    }
    for (int r = 0; r < 4; ++r) {
      int rl = wq + quad * 4 + r;
      int qi = q0 + rl;
      float vals[4], tmax = -1e30f;
      for (int j = 0; j < 4; ++j) {
        int ki = kt * 64 + j * 16 + m16;
        float xv = sc[j][r] * scale + bias[(size_t)qi * SEQ + ki];
        if (ki > qi) xv = -1e30f;
        vals[j] = xv;
        tmax = fmaxf(tmax, xv);
      }
      for (int off = 1; off < 16; off <<= 1) tmax = fmaxf(tmax, __shfl_xor(tmax, off));
      float mold = m_s[rl];
      float mnew = fmaxf(mold, tmax);
      float ssum = 0.f;
      for (int j = 0; j < 4; ++j) ssum += __expf(vals[j] - mnew);
      for (int off = 1; off < 16; off <<= 1) ssum += __shfl_xor(ssum, off);
      if (m16 == 0) {
        l_s[rl] = l_s[rl] * __expf(mold - mnew) + ssum;
        m_s[rl] = mnew;
      }
    }
  }
  __syncthreads();
  float mrow[4], linv[4];
  for (int r = 0; r < 4; ++r) {
    mrow[r] = m_s[wq + quad * 4 + r];
    linv[r] = 1.f / l_s[wq + quad * 4 + r];
  }

  f32x4 oacc[8];
  for (int d = 0; d < 8; ++d) oacc[d] = (f32x4){0.f, 0.f, 0.f, 0.f};
  float* Pg = P + (((size_t)(b * NH + h)) * SEQ + q0) * SEQ;

  // ---- phase 2: normalized P write + PV ----
  for (int kt = 0; kt <= qb; ++kt) {
    __syncthreads();
    const bf16_t* Kg = Kb + ((size_t)(b * SEQ + kt * 64)) * HID + h * DH;
    for (int it = 0; it < 4; ++it) {
      int g = it * 256 + tid, r = g >> 4, c = (g & 15) * 8;
      *(uint4*)&Ks[r * 136 + c] = *(const uint4*)(Kg + (size_t)r * HID + c);
    }
    const bf16_t* Vg = Vt + ((size_t)(b * NH + h)) * DH * SEQ + kt * 64;
    for (int it = 0; it < 4; ++it) {
      int g = it * 256 + tid, r = g >> 3, c = (g & 7) * 8;
      *(uint4*)&Vs[r * 72 + c] = *(const uint4*)(Vg + (size_t)r * SEQ + c);
    }
    __syncthreads();

    f32x4 sc[4];
    for (int j = 0; j < 4; ++j) sc[j] = (f32x4){0.f, 0.f, 0.f, 0.f};
    for (int ks = 0; ks < 4; ++ks) {
      bf16x8 af = *(const bf16x8*)&Qs[(wq + m16) * 136 + ks * 32 + quad * 8];
      for (int j = 0; j < 4; ++j) {
        bf16x8 bf_ = *(const bf16x8*)&Ks[(j * 16 + m16) * 136 + ks * 32 + quad * 8];
        sc[j] = __builtin_amdgcn_mfma_f32_16x16x32_bf16(af, bf_, sc[j], 0, 0, 0);
      }
    }
    for (int r = 0; r < 4; ++r) {
      int rl = wq + quad * 4 + r;
      int qi = q0 + rl;
      for (int j = 0; j < 4; ++j) {
        int ki = kt * 64 + j * 16 + m16;
        float xv = sc[j][r] * scale + bias[(size_t)qi * SEQ + ki];
        float p = (ki > qi) ? 0.f : __expf(xv - mrow[r]) * linv[r];
        Pg[(size_t)rl * SEQ + ki] = p;
        Ps[rl * 72 + j * 16 + m16] = f2bf(p);
      }
    }
    for (int ks = 0; ks < 2; ++ks) {
      bf16x8 pf = *(const bf16x8*)&Ps[(wq + m16) * 72 + ks * 32 + quad * 8];
      for (int dt = 0; dt < 8; ++dt) {
        bf16x8 vf = *(const bf16x8*)&Vs[(dt * 16 + m16) * 72 + ks * 32 + quad * 8];
        oacc[dt] = __builtin_amdgcn_mfma_f32_16x16x32_bf16(pf, vf, oacc[dt], 0, 0, 0);
      }
    }
  }

  // attn_out (bf16, [b*S+s][h*D+d])
  bf16_t* AOg = AO + ((size_t)(b * SEQ + q0)) * HID + h * DH;
  for (int r = 0; r < 4; ++r) {
    int rl = wq + quad * 4 + r;
    for (int dt = 0; dt < 8; ++dt)
      AOg[(size_t)rl * HID + dt * 16 + m16] = (bf16_t)oacc[dt][r];
  }

  // zero-fill masked upper-triangle columns of P
  int kz0 = (qb + 1) * 64;
  for (int r = 0; r < 64; ++r) {
    float4* dst = (float4*)(Pg + (size_t)r * SEQ);
    for (int c = kz0 / 4 + tid; c < SEQ / 4; c += 256) dst[c] = make_float4(0.f, 0.f, 0.f, 0.f);
  }
}

extern "C" void kernel_launch(void* const* d_in, const int* in_sizes, int n_in,
                              void* d_out, int out_size, void* d_ws, size_t ws_size,
                              hipStream_t stream) {
  const float* x = (const float*)d_in[0];
  const float* Wq = (const float*)d_in[1];
  const float* Wk = (const float*)d_in[2];
  const float* Wv = (const float*)d_in[3];
  const float* Wo = (const float*)d_in[4];
  const float* bias = (const float*)d_in[5];

  float* out = (float*)d_out;
  float* P = out + (size_t)BATCH * SEQ * HID;  // attn_weights section
  // park fp32 Q/K projections inside the (not yet written) P region
  float* Qf = P;
  float* Kf = P + (size_t)BATCH * SEQ * HID;

  char* w = (char*)d_ws;
  bf16_t* xb = (bf16_t*)w;  w += (size_t)BATCH * SEQ * HID * 2;
  bf16_t* Wqb = (bf16_t*)w; w += (size_t)HID * HID * 2;
  bf16_t* Wkb = (bf16_t*)w; w += (size_t)HID * HID * 2;
  bf16_t* Wvb = (bf16_t*)w; w += (size_t)HID * HID * 2;
  bf16_t* Wob = (bf16_t*)w; w += (size_t)HID * HID * 2;
  bf16_t* Qb = (bf16_t*)w;  w += (size_t)BATCH * SEQ * HID * 2;
  bf16_t* Kb = (bf16_t*)w;  w += (size_t)BATCH * SEQ * HID * 2;
  bf16_t* VtT = (bf16_t*)w; w += (size_t)BATCH * SEQ * HID * 2;
  bf16_t* AO = (bf16_t*)w;  w += (size_t)BATCH * SEQ * HID * 2;
  float* bm = (float*)w;    w += (size_t)SEQ * 4;

  const int n4x = BATCH * SEQ * HID / 4;
  const int n4w = HID * HID / 4;
  k_cast_bf16<<<(n4x + 255) / 256, 256, 0, stream>>>((const float4*)x, (ushort4*)xb, n4x);
  k_cast_bf16<<<(n4w + 255) / 256, 256, 0, stream>>>((const float4*)Wq, (ushort4*)Wqb, n4w);
  k_cast_bf16<<<(n4w + 255) / 256, 256, 0, stream>>>((const float4*)Wk, (ushort4*)Wkb, n4w);
  k_cast_bf16<<<(n4w + 255) / 256, 256, 0, stream>>>((const float4*)Wv, (ushort4*)Wvb, n4w);
  k_cast_bf16<<<(n4w + 255) / 256, 256, 0, stream>>>((const float4*)Wo, (ushort4*)Wob, n4w);
  k_bmean<<<SEQ, 256, 0, stream>>>(bias, bm);

  dim3 gg(HID / 128, BATCH * SEQ / 128);
  k_gemm_bt<0><<<gg, 256, 0, stream>>>(xb, Wqb, Qf, BATCH * SEQ, HID, HID);
  k_gemm_bt<0><<<gg, 256, 0, stream>>>(xb, Wkb, Kf, BATCH * SEQ, HID, HID);
  k_gemm_bt<2><<<gg, 256, 0, stream>>>(xb, Wvb, VtT, BATCH * SEQ, HID, HID);

  k_rope<<<(BATCH * SEQ * HID / 2) / 256, 256, 0, stream>>>(Qf, Kf, bm, Qb, Kb);

  k_attn<<<dim3(SEQ / 64, NH, BATCH), 256, 0, stream>>>(Qb, Kb, VtT, bias, P, AO);

  k_gemm_bt<0><<<gg, 256, 0, stream>>>(AO, Wob, out, BATCH * SEQ, HID, HID);
}

// Round 2
// 1236.348 us; speedup vs baseline: 1.5176x; 1.5176x over previous
//
#include <hip/hip_runtime.h>
#include <hip/hip_bf16.h>

typedef __bf16 bf16_t;
typedef __bf16 bf16x8 __attribute__((ext_vector_type(8)));
typedef float f32x4 __attribute__((ext_vector_type(4)));

#define SEQ 2048
#define HID 2048
#define NH 16
#define DH 128
#define BATCH 2

typedef __attribute__((address_space(1))) const unsigned int g_u32;
typedef __attribute__((address_space(3))) unsigned int l_u32;
#define GLOAD_LDS16(g, l) __builtin_amdgcn_global_load_lds((g_u32*)(g), (l_u32*)(l), 16, 0, 0)

__device__ __forceinline__ unsigned short f2bf(float f) {
  return __builtin_bit_cast(unsigned short, (__bf16)f);
}

// ---------------- cast fp32 -> bf16 ----------------
__global__ void k_cast_bf16(const float4* __restrict__ in, ushort4* __restrict__ out, int n4) {
  int i = blockIdx.x * 256 + threadIdx.x;
  if (i >= n4) return;
  float4 v = in[i];
  ushort4 o;
  o.x = f2bf(v.x); o.y = f2bf(v.y); o.z = f2bf(v.z); o.w = f2bf(v.w);
  out[i] = o;
}

// ---------------- bias row means (*0.1) ----------------
__global__ void k_bmean(const float* __restrict__ bias, float* __restrict__ bm) {
  int s = blockIdx.x;
  int t = threadIdx.x;
  const float4* row = (const float4*)(bias + (size_t)s * SEQ);
  float acc = 0.f;
  for (int c = t; c < SEQ / 4; c += 256) { float4 v = row[c]; acc += (v.x + v.y) + (v.z + v.w); }
  for (int off = 1; off < 64; off <<= 1) acc += __shfl_xor(acc, off);
  __shared__ float red[4];
  if ((t & 63) == 0) red[t >> 6] = acc;
  __syncthreads();
  if (t == 0) bm[s] = (red[0] + red[1] + red[2] + red[3]) * (0.1f / SEQ);
}

// ---------------- GEMM: C[M,N] = A[M,K] @ B[N,K]^T, m97-style global_load_lds + swizzle ----------------
// EPI 0: fp32 row-major; EPI 1: bf16 row-major
template <int EPI>
__global__ __launch_bounds__(256, 2) void k_gemm_bt(const bf16_t* __restrict__ A,
                                                    const bf16_t* __restrict__ B,
                                                    void* __restrict__ C,
                                                    int M, int N, int K) {
  __shared__ ushort As[128 * 64];  // unpadded, XOR-swizzled chunks of 8 bf16
  __shared__ ushort Bs[128 * 64];
  const int tid = threadIdx.x;
  const int lane = tid & 63, wave = tid >> 6;
  const int m16 = lane & 15, quad = lane >> 4;
  const int wm = (wave >> 1) * 64, wn = (wave & 1) * 64;
  const int bm0 = blockIdx.y * 128, bn0 = blockIdx.x * 128;

  f32x4 acc[4][4];
  for (int i = 0; i < 4; ++i)
    for (int j = 0; j < 4; ++j) acc[i][j] = (f32x4){0.f, 0.f, 0.f, 0.f};

  const int NT = K / 64;
  for (int kt = 0; kt < NT; ++kt) {
    __syncthreads();
    size_t k0 = (size_t)kt * 64;
    for (int it = 0; it < 4; ++it) {
      int g = it * 256 + tid;
      int r = g >> 3;                  // 64 cols = 8 chunks/row
      int c8 = (g & 7) ^ (r & 7);      // swizzled source chunk
      int base = (it * 256 + wave * 64) * 8;  // wave-uniform LDS ushort offset
      GLOAD_LDS16(A + (size_t)(bm0 + r) * K + k0 + c8 * 8, &As[base]);
      GLOAD_LDS16(B + (size_t)(bn0 + r) * K + k0 + c8 * 8, &Bs[base]);
    }
    __syncthreads();
    for (int ks = 0; ks < 2; ++ks) {
      bf16x8 af[4], bfr[4];
      for (int i = 0; i < 4; ++i) {
        int row = wm + i * 16 + m16;
        af[i] = *(const bf16x8*)&As[row * 64 + (((ks * 4 + quad) ^ (row & 7)) * 8)];
      }
      for (int j = 0; j < 4; ++j) {
        int row = wn + j * 16 + m16;
        bfr[j] = *(const bf16x8*)&Bs[row * 64 + (((ks * 4 + quad) ^ (row & 7)) * 8)];
      }
      for (int i = 0; i < 4; ++i)
        for (int j = 0; j < 4; ++j)
          acc[i][j] = __builtin_amdgcn_mfma_f32_16x16x32_bf16(af[i], bfr[j], acc[i][j], 0, 0, 0);
    }
  }
  for (int i = 0; i < 4; ++i)
    for (int j = 0; j < 4; ++j)
      for (int r = 0; r < 4; ++r) {
        int row = bm0 + wm + i * 16 + quad * 4 + r;
        int col = bn0 + wn + j * 16 + m16;
        float v = acc[i][j][r];
        if (EPI == 0) ((float*)C)[(size_t)row * N + col] = v;
        else          ((bf16_t*)C)[(size_t)row * N + col] = (bf16_t)v;
      }
}

// ---------------- V transpose: [b,s,hid] bf16 -> [b,h,d,s] bf16 ----------------
__global__ void k_vtrans(const bf16_t* __restrict__ Vr, bf16_t* __restrict__ Vt) {
  __shared__ ushort T[64 * 72];
  const int tid = threadIdx.x;
  const int s0 = blockIdx.x * 64, c0 = blockIdx.y * 64, b = blockIdx.z;
  const int h = c0 >> 7, d0 = c0 & (DH - 1);
  int r = tid >> 2, cc = (tid & 3) * 16;
  const bf16_t* src = Vr + ((size_t)(b * SEQ + s0 + r)) * HID + c0 + cc;
  *(uint4*)&T[r * 72 + cc] = *(const uint4*)src;
  *(uint4*)&T[r * 72 + cc + 8] = *(const uint4*)(src + 8);
  __syncthreads();
  int dr = tid >> 2, sc0 = (tid & 3) * 16;
  ushort tmp[16];
  for (int e = 0; e < 16; ++e) tmp[e] = T[(sc0 + e) * 72 + dr];
  bf16_t* dst = Vt + ((size_t)(b * NH + h) * DH + d0 + dr) * SEQ + s0 + sc0;
  *(uint4*)dst = *(uint4*)&tmp[0];
  *(uint4*)(dst + 8) = *(uint4*)&tmp[8];
}

// ---------------- RoPE + bmean, fp32 -> bf16 ----------------
__global__ void k_rope(const float* __restrict__ Qf, const float* __restrict__ Kf,
                       const float* __restrict__ bm,
                       bf16_t* __restrict__ Qb, bf16_t* __restrict__ Kb) {
  int idx = blockIdx.x * 256 + threadIdx.x;
  int row = idx >> 10, p = idx & 1023;
  int h = p >> 6, i = p & 63;
  int s = row & (SEQ - 1);
  float invf = powf(10000.f, -(float)i * (1.f / 64.f));
  float ang = (float)s * invf;
  float sn, cs;
  sincosf(ang, &sn, &cs);
  float b = bm[s];
  size_t o1 = (size_t)row * HID + h * DH + i;
  size_t o2 = o1 + 64;
  float q1 = Qf[o1], q2 = Qf[o2];
  Qb[o1] = (bf16_t)(q1 * cs - q2 * sn + b);
  Qb[o2] = (bf16_t)(q2 * cs + q1 * sn + b);
  float k1 = Kf[o1], k2 = Kf[o2];
  Kb[o1] = (bf16_t)(k1 * cs - k2 * sn + b);
  Kb[o2] = (bf16_t)(k2 * cs + k1 * sn + b);
}

// ---------------- attention ----------------
__global__ __launch_bounds__(256, 3) void k_attn(const bf16_t* __restrict__ Qb,
                                                 const bf16_t* __restrict__ Kb,
                                                 const bf16_t* __restrict__ Vt,
                                                 const float* __restrict__ bias,
                                                 float* __restrict__ P,
                                                 bf16_t* __restrict__ AO) {
  __shared__ ushort Qs[64 * 128];  // unpadded, swizzled
  __shared__ ushort Ks[64 * 128];  // unpadded, swizzled
  __shared__ ushort Ps[64 * 72];
  __shared__ ushort Bs[64 * 68];   // bias tile, bf16, stride 68

  const int tid = threadIdx.x;
  const int lane = tid & 63, wave = tid >> 6;
  const int m16 = lane & 15, quad = lane >> 4;
  const int qb = (int)gridDim.x - 1 - (int)blockIdx.x;  // big blocks first
  const int h = blockIdx.y, b = blockIdx.z;
  const int q0 = qb * 64;
  const int wq = wave * 16;
  const float scale = 0.08838834764831845f;

  // Q tile -> LDS (async, swizzled): 64 rows x 16 chunks
  const bf16_t* Qg = Qb + ((size_t)(b * SEQ + q0)) * HID + (size_t)h * DH;
  for (int it = 0; it < 4; ++it) {
    int g = it * 256 + tid;
    int r = g >> 4;
    int c16 = (g & 15) ^ (r & 15);
    GLOAD_LDS16(Qg + (size_t)r * HID + c16 * 8, &Qs[(it * 256 + wave * 64) * 8]);
  }

  const bf16_t* Kbase = Kb + ((size_t)b * SEQ) * HID + (size_t)h * DH;
  const float* bg = bias + (size_t)q0 * SEQ;

  float m_ln[4], l_ln[4];
  for (int r = 0; r < 4; ++r) { m_ln[r] = -1e30f; l_ln[r] = 0.f; }

  const int bR = tid >> 4, bC = (tid & 15) * 4;  // bias slot for it==0 (it adds 16 rows)
  float4 bpre[4];
  for (int it = 0; it < 4; ++it)
    bpre[it] = *(const float4*)(bg + (size_t)(bR + it * 16) * SEQ + bC);

  // ---- phase 1: exact row max / sumexp (per-lane online, no shuffles in loop) ----
  for (int kt = 0; kt <= qb; ++kt) {
    __syncthreads();
    const bf16_t* Kg = Kbase + (size_t)(kt * 64) * HID;
    for (int it = 0; it < 4; ++it) {
      int g = it * 256 + tid;
      int r = g >> 4;
      int c16 = (g & 15) ^ (r & 15);
      GLOAD_LDS16(Kg + (size_t)r * HID + c16 * 8, &Ks[(it * 256 + wave * 64) * 8]);
    }
    for (int it = 0; it < 4; ++it) {
      ushort4 o;
      o.x = f2bf(bpre[it].x); o.y = f2bf(bpre[it].y); o.z = f2bf(bpre[it].z); o.w = f2bf(bpre[it].w);
      *(ushort4*)&Bs[(bR + it * 16) * 68 + bC] = o;
    }
    __syncthreads();
    if (kt < qb)
      for (int it = 0; it < 4; ++it)
        bpre[it] = *(const float4*)(bg + (size_t)(bR + it * 16) * SEQ + (kt + 1) * 64 + bC);

    f32x4 sc[4];
    for (int j = 0; j < 4; ++j) sc[j] = (f32x4){0.f, 0.f, 0.f, 0.f};
    for (int ks = 0; ks < 4; ++ks) {
      int qrow = wq + m16;
      bf16x8 af = *(const bf16x8*)&Qs[qrow * 128 + (((ks * 4 + quad) ^ (qrow & 15)) * 8)];
      for (int j = 0; j < 4; ++j) {
        int krow = j * 16 + m16;
        bf16x8 bfr = *(const bf16x8*)&Ks[krow * 128 + (((ks * 4 + quad) ^ (krow & 15)) * 8)];
        sc[j] = __builtin_amdgcn_mfma_f32_16x16x32_bf16(af, bfr, sc[j], 0, 0, 0);
      }
    }
    for (int r = 0; r < 4; ++r) {
      int rl = wq + quad * 4 + r, qi = q0 + rl;
      float v[4], mx = m_ln[r];
      for (int j = 0; j < 4; ++j) {
        int ki = kt * 64 + j * 16 + m16;
        float bv = (float)(*(const bf16_t*)&Bs[rl * 68 + j * 16 + m16]);
        float xv = sc[j][r] * scale + bv;
        v[j] = (ki > qi) ? -1e30f : xv;
        mx = fmaxf(mx, v[j]);
      }
      float corr = __expf(m_ln[r] - mx);
      float s = __expf(v[0] - mx) + __expf(v[1] - mx) + __expf(v[2] - mx) + __expf(v[3] - mx);
      l_ln[r] = l_ln[r] * corr + s;
      m_ln[r] = mx;
    }
  }
  // combine across the 16 lanes sharing each row (within quad)
  float mrow[4], linv[4];
  for (int r = 0; r < 4; ++r) {
    float m = m_ln[r], l = l_ln[r];
    for (int off = 1; off < 16; off <<= 1) {
      float mo = __shfl_xor(m, off), lo = __shfl_xor(l, off);
      float mn = fmaxf(m, mo);
      l = l * __expf(m - mn) + lo * __expf(mo - mn);
      m = mn;
    }
    mrow[r] = m; linv[r] = 1.f / l;
  }

  f32x4 oacc[8];
  for (int d = 0; d < 8; ++d) oacc[d] = (f32x4){0.f, 0.f, 0.f, 0.f};
  float* Pg = P + (((size_t)(b * NH + h)) * SEQ + q0) * SEQ;
  const bf16_t* Vbase = Vt + ((size_t)(b * NH + h)) * DH * SEQ;

  for (int it = 0; it < 4; ++it)
    bpre[it] = *(const float4*)(bg + (size_t)(bR + it * 16) * SEQ + bC);

  // ---- phase 2: normalized P write + PV ----
  for (int kt = 0; kt <= qb; ++kt) {
    __syncthreads();
    const bf16_t* Kg = Kbase + (size_t)(kt * 64) * HID;
    for (int it = 0; it < 4; ++it) {
      int g = it * 256 + tid;
      int r = g >> 4;
      int c16 = (g & 15) ^ (r & 15);
      GLOAD_LDS16(Kg + (size_t)r * HID + c16 * 8, &Ks[(it * 256 + wave * 64) * 8]);
    }
    for (int it = 0; it < 4; ++it) {
      ushort4 o;
      o.x = f2bf(bpre[it].x); o.y = f2bf(bpre[it].y); o.z = f2bf(bpre[it].z); o.w = f2bf(bpre[it].w);
      *(ushort4*)&Bs[(bR + it * 16) * 68 + bC] = o;
    }
    __syncthreads();
    if (kt < qb)
      for (int it = 0; it < 4; ++it)
        bpre[it] = *(const float4*)(bg + (size_t)(bR + it * 16) * SEQ + (kt + 1) * 64 + bC);

    f32x4 sc[4];
    for (int j = 0; j < 4; ++j) sc[j] = (f32x4){0.f, 0.f, 0.f, 0.f};
    for (int ks = 0; ks < 4; ++ks) {
      int qrow = wq + m16;
      bf16x8 af = *(const bf16x8*)&Qs[qrow * 128 + (((ks * 4 + quad) ^ (qrow & 15)) * 8)];
      for (int j = 0; j < 4; ++j) {
        int krow = j * 16 + m16;
        bf16x8 bfr = *(const bf16x8*)&Ks[krow * 128 + (((ks * 4 + quad) ^ (krow & 15)) * 8)];
        sc[j] = __builtin_amdgcn_mfma_f32_16x16x32_bf16(af, bfr, sc[j], 0, 0, 0);
      }
    }

    // V fragments for first half (issue early; latency covered by softmax below)
    bf16x8 vf0[8];
    for (int dt = 0; dt < 8; ++dt)
      vf0[dt] = *(const bf16x8*)(Vbase + (size_t)(dt * 16 + m16) * SEQ + kt * 64 + quad * 8);

    for (int r = 0; r < 4; ++r) {
      int rl = wq + quad * 4 + r, qi = q0 + rl;
      for (int j = 0; j < 4; ++j) {
        int ki = kt * 64 + j * 16 + m16;
        float bv = (float)(*(const bf16_t*)&Bs[rl * 68 + j * 16 + m16]);
        float xv = sc[j][r] * scale + bv;
        float p = (ki > qi) ? 0.f : __expf(xv - mrow[r]) * linv[r];
        Pg[(size_t)rl * SEQ + ki] = p;
        Ps[rl * 72 + j * 16 + m16] = f2bf(p);
      }
    }

    bf16x8 vf1[8];
    for (int dt = 0; dt < 8; ++dt)
      vf1[dt] = *(const bf16x8*)(Vbase + (size_t)(dt * 16 + m16) * SEQ + kt * 64 + 32 + quad * 8);

    {
      bf16x8 pf = *(const bf16x8*)&Ps[(wq + m16) * 72 + quad * 8];
      for (int dt = 0; dt < 8; ++dt)
        oacc[dt] = __builtin_amdgcn_mfma_f32_16x16x32_bf16(pf, vf0[dt], oacc[dt], 0, 0, 0);
      pf = *(const bf16x8*)&Ps[(wq + m16) * 72 + 32 + quad * 8];
      for (int dt = 0; dt < 8; ++dt)
        oacc[dt] = __builtin_amdgcn_mfma_f32_16x16x32_bf16(pf, vf1[dt], oacc[dt], 0, 0, 0);
    }
  }

  // attn_out (bf16, [b*S+s][h*D+d])
  bf16_t* AOg = AO + ((size_t)(b * SEQ + q0)) * HID + (size_t)h * DH;
  for (int r = 0; r < 4; ++r) {
    int rl = wq + quad * 4 + r;
    for (int dt = 0; dt < 8; ++dt)
      AOg[(size_t)rl * HID + dt * 16 + m16] = (bf16_t)oacc[dt][r];
  }

  // zero-fill masked upper-triangle columns of P
  int kz0 = (qb + 1) * 64;
  for (int r = 0; r < 64; ++r) {
    float4* dst = (float4*)(Pg + (size_t)r * SEQ);
    for (int c = kz0 / 4 + tid; c < SEQ / 4; c += 256) dst[c] = make_float4(0.f, 0.f, 0.f, 0.f);
  }
}

extern "C" void kernel_launch(void* const* d_in, const int* in_sizes, int n_in,
                              void* d_out, int out_size, void* d_ws, size_t ws_size,
                              hipStream_t stream) {
  const float* x = (const float*)d_in[0];
  const float* Wq = (const float*)d_in[1];
  const float* Wk = (const float*)d_in[2];
  const float* Wv = (const float*)d_in[3];
  const float* Wo = (const float*)d_in[4];
  const float* bias = (const float*)d_in[5];

  float* out = (float*)d_out;
  float* P = out + (size_t)BATCH * SEQ * HID;  // attn_weights section (written last by k_attn)
  // park projection intermediates inside the not-yet-written P region
  float* Qf = P;
  float* Kf = P + (size_t)BATCH * SEQ * HID;
  bf16_t* Vr = (bf16_t*)(P + 2 * (size_t)BATCH * SEQ * HID);

  char* w = (char*)d_ws;
  bf16_t* xb = (bf16_t*)w;  w += (size_t)BATCH * SEQ * HID * 2;
  bf16_t* Wqb = (bf16_t*)w; w += (size_t)HID * HID * 2;
  bf16_t* Wkb = (bf16_t*)w; w += (size_t)HID * HID * 2;
  bf16_t* Wvb = (bf16_t*)w; w += (size_t)HID * HID * 2;
  bf16_t* Wob = (bf16_t*)w; w += (size_t)HID * HID * 2;
  bf16_t* Qb = (bf16_t*)w;  w += (size_t)BATCH * SEQ * HID * 2;
  bf16_t* Kb = (bf16_t*)w;  w += (size_t)BATCH * SEQ * HID * 2;
  bf16_t* Vt = (bf16_t*)w;  w += (size_t)BATCH * SEQ * HID * 2;
  bf16_t* AO = (bf16_t*)w;  w += (size_t)BATCH * SEQ * HID * 2;
  float* bm = (float*)w;    w += (size_t)SEQ * 4;

  const int n4x = BATCH * SEQ * HID / 4;
  const int n4w = HID * HID / 4;
  k_cast_bf16<<<(n4x + 255) / 256, 256, 0, stream>>>((const float4*)x, (ushort4*)xb, n4x);
  k_cast_bf16<<<(n4w + 255) / 256, 256, 0, stream>>>((const float4*)Wq, (ushort4*)Wqb, n4w);
  k_cast_bf16<<<(n4w + 255) / 256, 256, 0, stream>>>((const float4*)Wk, (ushort4*)Wkb, n4w);
  k_cast_bf16<<<(n4w + 255) / 256, 256, 0, stream>>>((const float4*)Wv, (ushort4*)Wvb, n4w);
  k_cast_bf16<<<(n4w + 255) / 256, 256, 0, stream>>>((const float4*)Wo, (ushort4*)Wob, n4w);
  k_bmean<<<SEQ, 256, 0, stream>>>(bias, bm);

  dim3 gg(HID / 128, BATCH * SEQ / 128);
  k_gemm_bt<0><<<gg, 256, 0, stream>>>(xb, Wqb, Qf, BATCH * SEQ, HID, HID);
  k_gemm_bt<0><<<gg, 256, 0, stream>>>(xb, Wkb, Kf, BATCH * SEQ, HID, HID);
  k_gemm_bt<1><<<gg, 256, 0, stream>>>(xb, Wvb, Vr, BATCH * SEQ, HID, HID);

  k_vtrans<<<dim3(SEQ / 64, HID / 64, BATCH), 256, 0, stream>>>(Vr, Vt);
  k_rope<<<(BATCH * SEQ * HID / 2) / 256, 256, 0, stream>>>(Qf, Kf, bm, Qb, Kb);

  k_attn<<<dim3(SEQ / 64, NH, BATCH), 256, 0, stream>>>(Qb, Kb, Vt, bias, P, AO);

  k_gemm_bt<0><<<gg, 256, 0, stream>>>(AO, Wob, out, BATCH * SEQ, HID, HID);
}